// Round 3
// baseline (16520.297 us; speedup 1.0000x reference)
//
#include <hip/hip_runtime.h>
#include <hip/hip_bf16.h>

#define DIM 16
#define N_ATM 131072
#define N_BND 1048576
#define N_ANG 2097152
#define N_GRAPHS 256
#define PI_F 3.14159265358979323846f

typedef __hip_bfloat16 bf16;

__device__ __forceinline__ float b2f(bf16 v) { return __bfloat162float(v); }
__device__ __forceinline__ float sigmoidf_(float x) { return 1.0f / (1.0f + __expf(-x)); }
__device__ __forceinline__ float siluf_(float x) { return x / (1.0f + __expf(-x)); }

// flag-aware scalar load: float data may be f32 or bf16 depending on harness
__device__ __forceinline__ float loadF(const void* p, long long i, int isbf) {
    return isbf ? b2f(((const bf16*)p)[i]) : ((const float*)p)[i];
}

__device__ __forceinline__ float bfbits2f(unsigned lo16) {
    union { unsigned u; float f; } c; c.u = lo16 << 16; return c.f;
}
__device__ __forceinline__ unsigned f2bfbits(float f) {
    union { float f; unsigned u; } c; c.f = f;
    unsigned u = c.u + 0x7FFFu + ((c.u >> 16) & 1u);  // RNE
    return u >> 16;
}

// ---- 16-wide row load/store for float or bf16 workspace storage ----
template <typename T> struct VecIO;
template <> struct VecIO<float> {
    static __device__ __forceinline__ void load16(const float* p, float* r) {
        const float4* q = (const float4*)p;
#pragma unroll
        for (int i = 0; i < 4; i++) { float4 v = q[i]; r[4*i]=v.x; r[4*i+1]=v.y; r[4*i+2]=v.z; r[4*i+3]=v.w; }
    }
    static __device__ __forceinline__ void store16(float* p, const float* r) {
        float4* q = (float4*)p;
#pragma unroll
        for (int i = 0; i < 4; i++) q[i] = make_float4(r[4*i], r[4*i+1], r[4*i+2], r[4*i+3]);
    }
};
template <> struct VecIO<bf16> {
    static __device__ __forceinline__ void load16(const bf16* p, float* r) {
        uint4 a = ((const uint4*)p)[0];
        uint4 b = ((const uint4*)p)[1];
        unsigned w[8] = {a.x, a.y, a.z, a.w, b.x, b.y, b.z, b.w};
#pragma unroll
        for (int i = 0; i < 8; i++) {
            r[2*i] = bfbits2f(w[i] & 0xFFFFu);
            union { unsigned u; float f; } c; c.u = w[i] & 0xFFFF0000u;
            r[2*i+1] = c.f;
        }
    }
    static __device__ __forceinline__ void store16(bf16* p, const float* r) {
        unsigned w[8];
#pragma unroll
        for (int i = 0; i < 8; i++)
            w[i] = f2bfbits(r[2*i]) | (f2bfbits(r[2*i+1]) << 16);
        ((uint4*)p)[0] = make_uint4(w[0], w[1], w[2], w[3]);
        ((uint4*)p)[1] = make_uint4(w[4], w[5], w[6], w[7]);
    }
};

// ---------- dtype detection ----------
// flags[0]: 1 if float tensors are bf16, 0 if f32.  (enc_ln_g is all-ones)
// flags[1]: 1 if mask is byte-bools, 0 if int32.
__global__ void k_flags(const void* lng, const void* mask, int* flags) {
    __shared__ int bad;
    if (threadIdx.x == 0) bad = 0;
    __syncthreads();
    const unsigned* mw = (const unsigned*)mask;
    int acc = 0;
    for (int i = threadIdx.x; i < 512 * 1024; i += 256)
        if (mw[i] > 1u) acc = 1;
    if (acc) atomicOr(&bad, 1);
    __syncthreads();
    if (threadIdx.x == 0) {
        unsigned w = *(const unsigned*)lng;
        flags[0] = (w == 0x3F803F80u) ? 1 : 0;
        flags[1] = bad;
    }
}

// ---------- zero fill ----------
__global__ void __launch_bounds__(256) k_zero(float4* __restrict__ p, int n4) {
    int i = blockIdx.x * 256 + threadIdx.x;
    if (i < n4) p[i] = make_float4(0.f, 0.f, 0.f, 0.f);
}

// ---------- convert (f32|bf16) -> f32 ----------
__global__ void k_cvt_any(const void* __restrict__ src, float* __restrict__ dst, int n,
                          const int* __restrict__ flags) {
    int i = blockIdx.x * blockDim.x + threadIdx.x;
    if (i < n) dst[i] = loadF(src, i, flags[0]);
}

// ---------- atom encoder ----------
__global__ void __launch_bounds__(256) k_enc_atm(
    const int* __restrict__ sp_in,
    const void* W1, const void* b1, const void* W2, const void* b2,
    const void* g, const void* be, const int* __restrict__ flags,
    float* __restrict__ out)
{
    __shared__ float sW1[256], sW2[256], sb1[16], sb2[16], sg[16], sbe[16];
    int t = threadIdx.x, isbf = flags[0];
    sW1[t] = loadF(W1, t, isbf); sW2[t] = loadF(W2, t, isbf);
    if (t < 16) { sb1[t]=loadF(b1,t,isbf); sb2[t]=loadF(b2,t,isbf); sg[t]=loadF(g,t,isbf); sbe[t]=loadF(be,t,isbf); }
    __syncthreads();
    int i = blockIdx.x * 256 + t;
    if (i >= N_ATM) return;
    int sp = sp_in[i]; sp = sp < 0 ? 0 : (sp > 15 ? 15 : sp);
    float h[16];
#pragma unroll
    for (int j = 0; j < 16; j++) h[j] = siluf_(sW1[sp * 16 + j] + sb1[j]);
    float o[16]; float mu = 0.f;
#pragma unroll
    for (int j = 0; j < 16; j++) {
        float a = sb2[j];
#pragma unroll
        for (int k = 0; k < 16; k++) a += h[k] * sW2[k * 16 + j];
        o[j] = a; mu += a;
    }
    mu *= (1.f / 16.f);
    float var = 0.f;
#pragma unroll
    for (int j = 0; j < 16; j++) { float d = o[j] - mu; var += d * d; }
    var *= (1.f / 16.f);
    float r = rsqrtf(var + 1e-5f);
    float ov[16];
#pragma unroll
    for (int j = 0; j < 16; j++) ov[j] = (o[j] - mu) * r * sg[j] + sbe[j];
    VecIO<float>::store16(out + (long long)i * 16, ov);
}

// ---------- bond encoder (enc set 1: element offsets W+256, vec+16) ----------
template <typename TO>
__global__ void __launch_bounds__(256) k_enc_bnd(
    const void* __restrict__ xb,
    const void* W1, const void* b1, const void* W2, const void* b2,
    const void* g, const void* be, const int* __restrict__ flags,
    TO* __restrict__ out)
{
    __shared__ float sW1[256], sW2[256], sb1[16], sb2[16], sg[16], sbe[16];
    int t = threadIdx.x, isbf = flags[0];
    sW1[t] = loadF(W1, 256 + t, isbf); sW2[t] = loadF(W2, 256 + t, isbf);
    if (t < 16) { sb1[t]=loadF(b1,16+t,isbf); sb2[t]=loadF(b2,16+t,isbf); sg[t]=loadF(g,16+t,isbf); sbe[t]=loadF(be,16+t,isbf); }
    __syncthreads();
    int i = blockIdx.x * 256 + t;
    if (i >= N_BND) return;
    float x = loadF(xb, i, isbf) + 1e-5f;
    const float c = 0.6324555320336759f; // sqrt(2/5)
    float inv = c / x;
    float feat[16];
#pragma unroll
    for (int k = 0; k < 16; k++) feat[k] = __sinf((float)(k + 1) * PI_F * x * 0.2f) * inv;
    float h[16];
#pragma unroll
    for (int j = 0; j < 16; j++) {
        float a = sb1[j];
#pragma unroll
        for (int k = 0; k < 16; k++) a += feat[k] * sW1[k * 16 + j];
        h[j] = siluf_(a);
    }
    float o[16]; float mu = 0.f;
#pragma unroll
    for (int j = 0; j < 16; j++) {
        float a = sb2[j];
#pragma unroll
        for (int k = 0; k < 16; k++) a += h[k] * sW2[k * 16 + j];
        o[j] = a; mu += a;
    }
    mu *= (1.f / 16.f);
    float var = 0.f;
#pragma unroll
    for (int j = 0; j < 16; j++) { float d = o[j] - mu; var += d * d; }
    var *= (1.f / 16.f);
    float r = rsqrtf(var + 1e-5f);
    float ov[16];
#pragma unroll
    for (int j = 0; j < 16; j++) ov[j] = (o[j] - mu) * r * sg[j] + sbe[j];
    VecIO<TO>::store16(out + (long long)i * 16, ov);
}

// ---------- angle encoder (enc sets 2/3; branch by mask) ----------
template <typename TO>
__global__ void __launch_bounds__(256) k_enc_ang(
    const void* __restrict__ xa, const void* __restrict__ mask,
    const void* W1, const void* b1, const void* W2, const void* b2,
    const void* g, const void* be, const int* __restrict__ flags,
    TO* __restrict__ out)
{
    __shared__ float sW1[512], sW2[512], sb1[32], sb2[32], sg[32], sbe[32];
    int t = threadIdx.x, isbf = flags[0], mbyte = flags[1];
    for (int i = t; i < 512; i += 256) { sW1[i] = loadF(W1, 512 + i, isbf); sW2[i] = loadF(W2, 512 + i, isbf); }
    if (t < 32) { sb1[t]=loadF(b1,32+t,isbf); sb2[t]=loadF(b2,32+t,isbf); sg[t]=loadF(g,32+t,isbf); sbe[t]=loadF(be,32+t,isbf); }
    __syncthreads();
    int i = blockIdx.x * 256 + t;
    if (i >= N_ANG) return;
    int m = mbyte ? (((const unsigned char*)mask)[i] != 0) : (((const int*)mask)[i] != 0);
    float x = loadF(xa, i, isbf);
    float gam = m ? 2.3873241463784303f : 4.7746482927568605f;   // 15/(2pi) : 15/pi
    float c0  = m ? -PI_F : 0.0f;
    float dc  = m ? 0.41887902047863906f : 0.20943951023931953f; // 2pi/15 : pi/15
    int wo = m * 256, vo = m * 16;
    float feat[16];
#pragma unroll
    for (int k = 0; k < 16; k++) {
        float d = gam * (x - (c0 + (float)k * dc));
        feat[k] = __expf(-d * d);
    }
    float h[16];
#pragma unroll
    for (int j = 0; j < 16; j++) {
        float a = sb1[vo + j];
#pragma unroll
        for (int k = 0; k < 16; k++) a += feat[k] * sW1[wo + k * 16 + j];
        h[j] = siluf_(a);
    }
    float o[16]; float mu = 0.f;
#pragma unroll
    for (int j = 0; j < 16; j++) {
        float a = sb2[vo + j];
#pragma unroll
        for (int k = 0; k < 16; k++) a += h[k] * sW2[wo + k * 16 + j];
        o[j] = a; mu += a;
    }
    mu *= (1.f / 16.f);
    float var = 0.f;
#pragma unroll
    for (int j = 0; j < 16; j++) { float d = o[j] - mu; var += d * d; }
    var *= (1.f / 16.f);
    float r = rsqrtf(var + 1e-5f);
    float ov[16];
#pragma unroll
    for (int j = 0; j < 16; j++) ov[j] = (o[j] - mu) * r * sg[vo + j] + sbe[vo + j];
    VecIO<TO>::store16(out + (long long)i * 16, ov);
}

// ---------- edge-gated conv: edge kernel ----------
template <typename TX, typename TE>
__global__ void __launch_bounds__(256) k_edge(
    const TX* __restrict__ x, TE* __restrict__ e,
    const int* __restrict__ src, const int* __restrict__ dst,
    const float* __restrict__ W, const float* __restrict__ b0,
    const float* __restrict__ lnE,
    float* __restrict__ num, float* __restrict__ den, int E, int NX)
{
    int i = blockIdx.x * 256 + threadIdx.x;
    if (i >= E) return;
    int s = src[i], d = dst[i];
    s = s < 0 ? 0 : (s >= NX ? NX - 1 : s);
    d = d < 0 ? 0 : (d >= NX ? NX - 1 : d);
    float xs[16], xd[16], ev[16];
    VecIO<TX>::load16(x + (long long)s * 16, xs);
    VecIO<TX>::load16(x + (long long)d * 16, xd);
    VecIO<TE>::load16(e + (long long)i * 16, ev);
    float z[16], mm[16];
#pragma unroll
    for (int j = 0; j < 16; j++) { z[j] = b0[j]; mm[j] = 0.f; }
#pragma unroll
    for (int k = 0; k < 16; k++) {
        float a = xs[k], c = xd[k], q = ev[k];
#pragma unroll
        for (int j = 0; j < 16; j++) {
            z[j] += a * W[k * 16 + j] + c * W[256 + k * 16 + j] + q * W[512 + k * 16 + j];
            mm[j] += a * W[1024 + k * 16 + j];
        }
    }
    float* nrow = num + (long long)d * 16;
    float* drow = den + (long long)d * 16;
    float mu = 0.f;
#pragma unroll
    for (int j = 0; j < 16; j++) {
        float sg_ = sigmoidf_(z[j]);
        atomicAdd(&nrow[j], sg_ * mm[j]);
        atomicAdd(&drow[j], sg_);
        mu += z[j];
    }
    mu *= (1.f / 16.f);
    float var = 0.f;
#pragma unroll
    for (int j = 0; j < 16; j++) { float dd = z[j] - mu; var += dd * dd; }
    var *= (1.f / 16.f);
    float r = rsqrtf(var + 1e-5f);
    float ov[16];
#pragma unroll
    for (int j = 0; j < 16; j++)
        ov[j] = ev[j] + siluf_((z[j] - mu) * r * lnE[j] + lnE[16 + j]);
    VecIO<TE>::store16(e + (long long)i * 16, ov);
}

// ---------- edge-gated conv: node kernel ----------
template <typename TX>
__global__ void __launch_bounds__(256) k_node(
    TX* __restrict__ x,
    const float* __restrict__ W3, const float* __restrict__ b1,
    const float* __restrict__ lnN,
    const float* __restrict__ num, const float* __restrict__ den, int n)
{
    int i = blockIdx.x * 256 + threadIdx.x;
    if (i >= n) return;
    float xv[16];
    VecIO<TX>::load16(x + (long long)i * 16, xv);
    float nv[16], dv[16];
    VecIO<float>::load16(num + (long long)i * 16, nv);
    VecIO<float>::load16(den + (long long)i * 16, dv);
    float t[16]; float mu = 0.f;
#pragma unroll
    for (int j = 0; j < 16; j++) {
        float a = b1[j] + nv[j] / (dv[j] + 1e-5f);
#pragma unroll
        for (int k = 0; k < 16; k++) a += xv[k] * W3[k * 16 + j];
        t[j] = a; mu += a;
    }
    mu *= (1.f / 16.f);
    float var = 0.f;
#pragma unroll
    for (int j = 0; j < 16; j++) { float dd = t[j] - mu; var += dd * dd; }
    var *= (1.f / 16.f);
    float r = rsqrtf(var + 1e-5f);
    float ov[16];
#pragma unroll
    for (int j = 0; j < 16; j++)
        ov[j] = xv[j] + siluf_((t[j] - mu) * r * lnN[j] + lnN[16 + j]);
    VecIO<TX>::store16(x + (long long)i * 16, ov);
}

// ---------- pooling ----------
__global__ void __launch_bounds__(256) k_pool(
    const float* __restrict__ h, const int* __restrict__ batch,
    float* __restrict__ pooled, int n)
{
    int i = blockIdx.x * 256 + threadIdx.x;
    if (i >= n) return;
    int g = batch[i]; g = g < 0 ? 0 : (g > N_GRAPHS - 1 ? N_GRAPHS - 1 : g);
#pragma unroll
    for (int j = 0; j < 16; j++) atomicAdd(&pooled[g * 16 + j], h[(long long)i * 16 + j]);
}

// ---------- head ----------
__global__ void __launch_bounds__(256) k_head(
    const float* __restrict__ pooled, const void* __restrict__ fp,
    const void* l1W, const void* l1b, const void* l2W, const void* l2b,
    const int* __restrict__ flags, void* __restrict__ out)
{
    __shared__ float sW[18 * 16], sb[16], s2W[16];
    int t = threadIdx.x, isbf = flags[0];
    for (int i = t; i < 288; i += 256) sW[i] = loadF(l1W, i, isbf);
    if (t < 16) { sb[t] = loadF(l1b, t, isbf); s2W[t] = loadF(l2W, t, isbf); }
    __syncthreads();
    int g = t;
    if (g >= N_GRAPHS) return;
    float in[18];
#pragma unroll
    for (int j = 0; j < 16; j++) in[j] = pooled[g * 16 + j];
    in[16] = loadF(fp, 2 * g, isbf);
    in[17] = loadF(fp, 2 * g + 1, isbf);
    float acc = loadF(l2b, 0, isbf);
#pragma unroll
    for (int j = 0; j < 16; j++) {
        float h = sb[j];
#pragma unroll
        for (int k = 0; k < 18; k++) h += in[k] * sW[k * 16 + j];
        h = (h > 0.f) ? h : 0.01f * h;
        acc += h * s2W[j];
    }
    if (isbf) ((bf16*)out)[g] = __float2bfloat16(acc);
    else      ((float*)out)[g] = acc;
}

// ---------- full pipeline, templated on h_bnd / h_ang storage ----------
template <typename TB, typename TA>
static void run_pipeline(void* const* d_in, void* d_out, void* d_ws, hipStream_t stream) {
    const int*  x_atm  = (const int*)d_in[0];
    const void* x_bnd  = d_in[1];
    const void* x_ang  = d_in[2];
    const void* mask   = d_in[3];
    const int*  eiG    = (const int*)d_in[4];
    const int*  eiA    = (const int*)d_in[5];
    const int*  batch  = (const int*)d_in[6];
    const void* fp     = d_in[7];
    const void* eW1    = d_in[8];
    const void* eb1    = d_in[9];
    const void* eW2    = d_in[10];
    const void* eb2    = d_in[11];
    const void* elg    = d_in[12];
    const void* elb    = d_in[13];
    const void* convW  = d_in[14];
    const void* convB  = d_in[15];
    const void* convLN = d_in[16];
    const void* l1W    = d_in[17];
    const void* l1b    = d_in[18];
    const void* l2W    = d_in[19];
    const void* l2b    = d_in[20];

    const size_t NA16 = (size_t)N_ATM * 16;
    const size_t NB16 = (size_t)N_BND * 16;
    const size_t NG16 = (size_t)N_ANG * 16;

    char* p = (char*)d_ws;
    int*   flags  = (int*)p;   p += 256;
    float* cw     = (float*)p; p += 7680 * sizeof(float);
    float* cb     = (float*)p; p += 192 * sizeof(float);
    float* cln    = (float*)p; p += 384 * sizeof(float);
    float* pooled = (float*)p; p += 4096 * sizeof(float);
    float* h_atm  = (float*)p; p += NA16 * sizeof(float);
    TB*    h_bnd  = (TB*)p;    p += NB16 * sizeof(TB);
    TA*    h_ang  = (TA*)p;    p += NG16 * sizeof(TA);
    float* nd     = (float*)p;

    k_flags<<<1, 256, 0, stream>>>(elg, mask, flags);

    k_cvt_any<<<30, 256, 0, stream>>>(convW, cw, 7680, flags);
    k_cvt_any<<<1, 256, 0, stream>>>(convB, cb, 192, flags);
    k_cvt_any<<<2, 256, 0, stream>>>(convLN, cln, 384, flags);

    k_enc_atm<<<N_ATM / 256, 256, 0, stream>>>(x_atm, eW1, eb1, eW2, eb2, elg, elb, flags, h_atm);
    k_enc_bnd<TB><<<N_BND / 256, 256, 0, stream>>>(x_bnd, eW1, eb1, eW2, eb2, elg, elb, flags, h_bnd);
    k_enc_ang<TA><<<N_ANG / 256, 256, 0, stream>>>(x_ang, mask, eW1, eb1, eW2, eb2, elg, elb, flags, h_ang);

    for (int c = 0; c < 3; c++) {
        {   // line-graph conv: x = h_bnd, e = h_ang, edges = A (2M)
            const float* W = cw + (size_t)(c * 2 + 0) * 5 * 256;
            const float* B = cb + (size_t)(c * 2 + 0) * 32;
            const float* L = cln + (size_t)(c * 2 + 0) * 64;
            k_zero<<<(int)((2 * NB16 / 4 + 255) / 256), 256, 0, stream>>>((float4*)nd, (int)(2 * NB16 / 4));
            k_edge<TB, TA><<<N_ANG / 256, 256, 0, stream>>>(h_bnd, h_ang, eiA, eiA + N_ANG,
                                                            W, B, L + 32, nd, nd + NB16, N_ANG, N_BND);
            k_node<TB><<<N_BND / 256, 256, 0, stream>>>(h_bnd, W + 768, B + 16, L, nd, nd + NB16, N_BND);
        }
        {   // atom-graph conv: x = h_atm (f32), e = h_bnd, edges = G (1M)
            const float* W = cw + (size_t)(c * 2 + 1) * 5 * 256;
            const float* B = cb + (size_t)(c * 2 + 1) * 32;
            const float* L = cln + (size_t)(c * 2 + 1) * 64;
            k_zero<<<(int)((2 * NA16 / 4 + 255) / 256), 256, 0, stream>>>((float4*)nd, (int)(2 * NA16 / 4));
            k_edge<float, TB><<<N_BND / 256, 256, 0, stream>>>(h_atm, h_bnd, eiG, eiG + N_BND,
                                                               W, B, L + 32, nd, nd + NA16, N_BND, N_ATM);
            k_node<float><<<N_ATM / 256, 256, 0, stream>>>(h_atm, W + 768, B + 16, L, nd, nd + NA16, N_ATM);
        }
    }

    k_zero<<<4, 256, 0, stream>>>((float4*)pooled, 1024);
    k_pool<<<N_ATM / 256, 256, 0, stream>>>(h_atm, batch, pooled, N_ATM);
    k_head<<<1, 256, 0, stream>>>(pooled, fp, l1W, l1b, l2W, l2b, flags, d_out);
}

extern "C" void kernel_launch(void* const* d_in, const int* in_sizes, int n_in,
                              void* d_out, int out_size, void* d_ws, size_t ws_size,
                              hipStream_t stream) {
    const size_t NA16 = (size_t)N_ATM * 16;
    const size_t NB16 = (size_t)N_BND * 16;
    const size_t NG16 = (size_t)N_ANG * 16;
    const size_t small = 256 + (7680 + 192 + 384 + 4096) * 4;
    auto need = [&](size_t szB, size_t szA) {
        return small + NA16 * 4 + NB16 * szB + NG16 * szA + 2 * NB16 * 4;
    };
    if (ws_size >= need(4, 4))        run_pipeline<float, float>(d_in, d_out, d_ws, stream);
    else if (ws_size >= need(4, 2))   run_pipeline<float, bf16>(d_in, d_out, d_ws, stream);
    else                              run_pipeline<bf16, bf16>(d_in, d_out, d_ws, stream);
}

// Round 4
// 14081.609 us; speedup vs baseline: 1.1732x; 1.1732x over previous
//
#include <hip/hip_runtime.h>
#include <hip/hip_bf16.h>

#define DIM 16
#define N_ATM 131072
#define N_BND 1048576
#define N_ANG 2097152
#define N_GRAPHS 256
#define PI_F 3.14159265358979323846f

typedef __hip_bfloat16 bf16;

__device__ __forceinline__ float b2f(bf16 v) { return __bfloat162float(v); }
__device__ __forceinline__ float sigmoidf_(float x) { return 1.0f / (1.0f + __expf(-x)); }
__device__ __forceinline__ float siluf_(float x) { return x / (1.0f + __expf(-x)); }

// flag-aware scalar load: float data may be f32 or bf16 depending on harness
__device__ __forceinline__ float loadF(const void* p, long long i, int isbf) {
    return isbf ? b2f(((const bf16*)p)[i]) : ((const float*)p)[i];
}

__device__ __forceinline__ float bfbits2f(unsigned lo16) {
    union { unsigned u; float f; } c; c.u = lo16 << 16; return c.f;
}
__device__ __forceinline__ unsigned f2bfbits(float f) {
    union { float f; unsigned u; } c; c.f = f;
    unsigned u = c.u + 0x7FFFu + ((c.u >> 16) & 1u);  // RNE
    return u >> 16;
}

// ---- 16-wide row load/store for float or bf16 workspace storage ----
template <typename T> struct VecIO;
template <> struct VecIO<float> {
    static __device__ __forceinline__ void load16(const float* p, float* r) {
        const float4* q = (const float4*)p;
#pragma unroll
        for (int i = 0; i < 4; i++) { float4 v = q[i]; r[4*i]=v.x; r[4*i+1]=v.y; r[4*i+2]=v.z; r[4*i+3]=v.w; }
    }
    static __device__ __forceinline__ void store16(float* p, const float* r) {
        float4* q = (float4*)p;
#pragma unroll
        for (int i = 0; i < 4; i++) q[i] = make_float4(r[4*i], r[4*i+1], r[4*i+2], r[4*i+3]);
    }
};
template <> struct VecIO<bf16> {
    static __device__ __forceinline__ void load16(const bf16* p, float* r) {
        uint4 a = ((const uint4*)p)[0];
        uint4 b = ((const uint4*)p)[1];
        unsigned w[8] = {a.x, a.y, a.z, a.w, b.x, b.y, b.z, b.w};
#pragma unroll
        for (int i = 0; i < 8; i++) {
            r[2*i] = bfbits2f(w[i] & 0xFFFFu);
            union { unsigned u; float f; } c; c.u = w[i] & 0xFFFF0000u;
            r[2*i+1] = c.f;
        }
    }
    static __device__ __forceinline__ void store16(bf16* p, const float* r) {
        unsigned w[8];
#pragma unroll
        for (int i = 0; i < 8; i++)
            w[i] = f2bfbits(r[2*i]) | (f2bfbits(r[2*i+1]) << 16);
        ((uint4*)p)[0] = make_uint4(w[0], w[1], w[2], w[3]);
        ((uint4*)p)[1] = make_uint4(w[4], w[5], w[6], w[7]);
    }
};

// ---------- small utility kernels ----------
__global__ void __launch_bounds__(256) k_zero_int(int* __restrict__ p, int n) {
    int i = blockIdx.x * 256 + threadIdx.x;
    if (i < n) p[i] = 0;
}
__global__ void __launch_bounds__(256) k_zero(float4* __restrict__ p, int n4) {
    int i = blockIdx.x * 256 + threadIdx.x;
    if (i < n4) p[i] = make_float4(0.f, 0.f, 0.f, 0.f);
}

// ---------- dtype detection (parallel) ----------
// flags[0]: 1 if float tensors are bf16, 0 if f32.  flags[1]: 1 if mask is byte-bools.
__global__ void __launch_bounds__(256) k_detect(const void* lng, const unsigned* __restrict__ mask,
                                                int* flags) {
    int i = blockIdx.x * 256 + threadIdx.x;
    if (i == 0) flags[0] = (*(const unsigned*)lng == 0x3F803F80u) ? 1 : 0;
    int bad = 0;
    for (int j = i; j < 512 * 1024; j += 512 * 256)
        if (mask[j] > 1u) bad = 1;
    if (bad) atomicOr(&flags[1], 1);
}

// ---------- convert (f32|bf16) -> f32 ----------
__global__ void k_cvt_any(const void* __restrict__ src, float* __restrict__ dst, int n,
                          const int* __restrict__ flags) {
    int i = blockIdx.x * blockDim.x + threadIdx.x;
    if (i < n) dst[i] = loadF(src, i, flags[0]);
}

// ---------- CSR build ----------
__global__ void __launch_bounds__(256) k_count(const int* __restrict__ dst, int* __restrict__ cnt,
                                               int E, int n) {
    int i = blockIdx.x * 256 + threadIdx.x;
    if (i >= E) return;
    int d = dst[i]; d = d < 0 ? 0 : (d >= n ? n - 1 : d);
    atomicAdd(&cnt[d], 1);
}
__global__ void __launch_bounds__(256) k_scan_local(const int* __restrict__ cnt, int* __restrict__ ofs,
                                                    int* __restrict__ bsum, int n) {
    __shared__ int s[256];
    int t = threadIdx.x, i = blockIdx.x * 256 + t;
    int v = (i < n) ? cnt[i] : 0;
    s[t] = v; __syncthreads();
    for (int o = 1; o < 256; o <<= 1) {
        int add = (t >= o) ? s[t - o] : 0;
        __syncthreads();
        s[t] += add;
        __syncthreads();
    }
    if (i < n) ofs[i] = s[t] - v;         // block-local exclusive
    if (t == 255) bsum[blockIdx.x] = s[255];
}
__global__ void __launch_bounds__(256) k_scan_bsum(int* __restrict__ bsum, int nb) {
    __shared__ int s[256];
    __shared__ int run;
    int t = threadIdx.x;
    if (t == 0) run = 0;
    __syncthreads();
    for (int base = 0; base < nb; base += 256) {
        int i = base + t;
        int v = (i < nb) ? bsum[i] : 0;
        s[t] = v; __syncthreads();
        for (int o = 1; o < 256; o <<= 1) {
            int add = (t >= o) ? s[t - o] : 0;
            __syncthreads();
            s[t] += add;
            __syncthreads();
        }
        if (i < nb) bsum[i] = run + s[t] - v;   // exclusive across whole
        __syncthreads();
        if (t == 0) run += s[255];
        __syncthreads();
    }
}
__global__ void __launch_bounds__(256) k_scan_add(int* __restrict__ ofs, const int* __restrict__ bsum,
                                                  int* __restrict__ cursor, int n) {
    int i = blockIdx.x * 256 + threadIdx.x;
    if (i < n) { int v = ofs[i] + bsum[blockIdx.x]; ofs[i] = v; cursor[i] = v; }
}
__global__ void __launch_bounds__(256) k_scatter(const int* __restrict__ dst, int* __restrict__ cur,
                                                 int* __restrict__ eid, int E, int n) {
    int i = blockIdx.x * 256 + threadIdx.x;
    if (i >= E) return;
    int d = dst[i]; d = d < 0 ? 0 : (d >= n ? n - 1 : d);
    int pos = atomicAdd(&cur[d], 1);
    eid[pos] = i;
}
// after k_scatter: ofs[d] = start, cur[d] = end

// ---------- encoders (unchanged from round 3) ----------
__global__ void __launch_bounds__(256) k_enc_atm(
    const int* __restrict__ sp_in,
    const void* W1, const void* b1, const void* W2, const void* b2,
    const void* g, const void* be, const int* __restrict__ flags,
    float* __restrict__ out)
{
    __shared__ float sW1[256], sW2[256], sb1[16], sb2[16], sg[16], sbe[16];
    int t = threadIdx.x, isbf = flags[0];
    sW1[t] = loadF(W1, t, isbf); sW2[t] = loadF(W2, t, isbf);
    if (t < 16) { sb1[t]=loadF(b1,t,isbf); sb2[t]=loadF(b2,t,isbf); sg[t]=loadF(g,t,isbf); sbe[t]=loadF(be,t,isbf); }
    __syncthreads();
    int i = blockIdx.x * 256 + t;
    if (i >= N_ATM) return;
    int sp = sp_in[i]; sp = sp < 0 ? 0 : (sp > 15 ? 15 : sp);
    float h[16];
#pragma unroll
    for (int j = 0; j < 16; j++) h[j] = siluf_(sW1[sp * 16 + j] + sb1[j]);
    float o[16]; float mu = 0.f;
#pragma unroll
    for (int j = 0; j < 16; j++) {
        float a = sb2[j];
#pragma unroll
        for (int k = 0; k < 16; k++) a += h[k] * sW2[k * 16 + j];
        o[j] = a; mu += a;
    }
    mu *= (1.f / 16.f);
    float var = 0.f;
#pragma unroll
    for (int j = 0; j < 16; j++) { float d = o[j] - mu; var += d * d; }
    var *= (1.f / 16.f);
    float r = rsqrtf(var + 1e-5f);
    float ov[16];
#pragma unroll
    for (int j = 0; j < 16; j++) ov[j] = (o[j] - mu) * r * sg[j] + sbe[j];
    VecIO<float>::store16(out + (long long)i * 16, ov);
}

template <typename TO>
__global__ void __launch_bounds__(256) k_enc_bnd(
    const void* __restrict__ xb,
    const void* W1, const void* b1, const void* W2, const void* b2,
    const void* g, const void* be, const int* __restrict__ flags,
    TO* __restrict__ out)
{
    __shared__ float sW1[256], sW2[256], sb1[16], sb2[16], sg[16], sbe[16];
    int t = threadIdx.x, isbf = flags[0];
    sW1[t] = loadF(W1, 256 + t, isbf); sW2[t] = loadF(W2, 256 + t, isbf);
    if (t < 16) { sb1[t]=loadF(b1,16+t,isbf); sb2[t]=loadF(b2,16+t,isbf); sg[t]=loadF(g,16+t,isbf); sbe[t]=loadF(be,16+t,isbf); }
    __syncthreads();
    int i = blockIdx.x * 256 + t;
    if (i >= N_BND) return;
    float x = loadF(xb, i, isbf) + 1e-5f;
    const float c = 0.6324555320336759f; // sqrt(2/5)
    float inv = c / x;
    float feat[16];
#pragma unroll
    for (int k = 0; k < 16; k++) feat[k] = __sinf((float)(k + 1) * PI_F * x * 0.2f) * inv;
    float h[16];
#pragma unroll
    for (int j = 0; j < 16; j++) {
        float a = sb1[j];
#pragma unroll
        for (int k = 0; k < 16; k++) a += feat[k] * sW1[k * 16 + j];
        h[j] = siluf_(a);
    }
    float o[16]; float mu = 0.f;
#pragma unroll
    for (int j = 0; j < 16; j++) {
        float a = sb2[j];
#pragma unroll
        for (int k = 0; k < 16; k++) a += h[k] * sW2[k * 16 + j];
        o[j] = a; mu += a;
    }
    mu *= (1.f / 16.f);
    float var = 0.f;
#pragma unroll
    for (int j = 0; j < 16; j++) { float d = o[j] - mu; var += d * d; }
    var *= (1.f / 16.f);
    float r = rsqrtf(var + 1e-5f);
    float ov[16];
#pragma unroll
    for (int j = 0; j < 16; j++) ov[j] = (o[j] - mu) * r * sg[j] + sbe[j];
    VecIO<TO>::store16(out + (long long)i * 16, ov);
}

template <typename TO>
__global__ void __launch_bounds__(256) k_enc_ang(
    const void* __restrict__ xa, const void* __restrict__ mask,
    const void* W1, const void* b1, const void* W2, const void* b2,
    const void* g, const void* be, const int* __restrict__ flags,
    TO* __restrict__ out)
{
    __shared__ float sW1[512], sW2[512], sb1[32], sb2[32], sg[32], sbe[32];
    int t = threadIdx.x, isbf = flags[0], mbyte = flags[1];
    for (int i = t; i < 512; i += 256) { sW1[i] = loadF(W1, 512 + i, isbf); sW2[i] = loadF(W2, 512 + i, isbf); }
    if (t < 32) { sb1[t]=loadF(b1,32+t,isbf); sb2[t]=loadF(b2,32+t,isbf); sg[t]=loadF(g,32+t,isbf); sbe[t]=loadF(be,32+t,isbf); }
    __syncthreads();
    int i = blockIdx.x * 256 + t;
    if (i >= N_ANG) return;
    int m = mbyte ? (((const unsigned char*)mask)[i] != 0) : (((const int*)mask)[i] != 0);
    float x = loadF(xa, i, isbf);
    float gam = m ? 2.3873241463784303f : 4.7746482927568605f;   // 15/(2pi) : 15/pi
    float c0  = m ? -PI_F : 0.0f;
    float dc  = m ? 0.41887902047863906f : 0.20943951023931953f; // 2pi/15 : pi/15
    int wo = m * 256, vo = m * 16;
    float feat[16];
#pragma unroll
    for (int k = 0; k < 16; k++) {
        float d = gam * (x - (c0 + (float)k * dc));
        feat[k] = __expf(-d * d);
    }
    float h[16];
#pragma unroll
    for (int j = 0; j < 16; j++) {
        float a = sb1[vo + j];
#pragma unroll
        for (int k = 0; k < 16; k++) a += feat[k] * sW1[wo + k * 16 + j];
        h[j] = siluf_(a);
    }
    float o[16]; float mu = 0.f;
#pragma unroll
    for (int j = 0; j < 16; j++) {
        float a = sb2[vo + j];
#pragma unroll
        for (int k = 0; k < 16; k++) a += h[k] * sW2[wo + k * 16 + j];
        o[j] = a; mu += a;
    }
    mu *= (1.f / 16.f);
    float var = 0.f;
#pragma unroll
    for (int j = 0; j < 16; j++) { float d = o[j] - mu; var += d * d; }
    var *= (1.f / 16.f);
    float r = rsqrtf(var + 1e-5f);
    float ov[16];
#pragma unroll
    for (int j = 0; j < 16; j++) ov[j] = (o[j] - mu) * r * sg[vo + j] + sbe[vo + j];
    VecIO<TO>::store16(out + (long long)i * 16, ov);
}

// ---------- fused edge-gated conv (gather form, atomic-free) ----------
// One thread per dst node. For each incoming edge (CSR): recompute z from OLD
// x/e, update e in place (each edge owned by exactly one dst), accumulate
// num/den in registers. Then node update into x_new (ping-pong).
template <typename TX, typename TE>
__global__ void __launch_bounds__(256) k_conv(
    const TX* __restrict__ x_old, TX* __restrict__ x_new, TE* __restrict__ e,
    const int* __restrict__ src, const int* __restrict__ eid,
    const int* __restrict__ ofs, const int* __restrict__ endo,
    const float* __restrict__ W,  // [5,16,16]
    const float* __restrict__ B,  // [32]: b0, b1
    const float* __restrict__ L,  // [64]: nodeG,nodeB,edgeG,edgeB
    int n, int nsrc)
{
    __shared__ float sW[1280], sB[32], sL[64];
    int t = threadIdx.x;
    for (int i = t; i < 1280; i += 256) sW[i] = W[i];
    if (t < 32) sB[t] = B[t];
    if (t < 64) sL[t] = L[t];
    __syncthreads();
    int d = blockIdx.x * 256 + t;
    if (d >= n) return;
    float xv[16];
    VecIO<TX>::load16(x_old + (long long)d * 16, xv);
    float num[16], den[16];
#pragma unroll
    for (int j = 0; j < 16; j++) { num[j] = 0.f; den[j] = 0.f; }
    int p0 = ofs[d], p1 = endo[d];
    for (int p = p0; p < p1; p++) {
        int ei = eid[p];
        int s = src[ei]; s = s < 0 ? 0 : (s >= nsrc ? nsrc - 1 : s);
        float xs[16], ev[16];
        VecIO<TX>::load16(x_old + (long long)s * 16, xs);
        VecIO<TE>::load16(e + (long long)ei * 16, ev);
        float z[16], mm[16];
#pragma unroll
        for (int j = 0; j < 16; j++) { z[j] = sB[j]; mm[j] = 0.f; }
#pragma unroll
        for (int k = 0; k < 16; k++) {
            float a = xs[k], c = xv[k], q = ev[k];
#pragma unroll
            for (int j = 0; j < 16; j++) {
                z[j] += a * sW[k * 16 + j] + c * sW[256 + k * 16 + j] + q * sW[512 + k * 16 + j];
                mm[j] += a * sW[1024 + k * 16 + j];
            }
        }
        float mu = 0.f;
#pragma unroll
        for (int j = 0; j < 16; j++) mu += z[j];
        mu *= (1.f / 16.f);
        float var = 0.f;
#pragma unroll
        for (int j = 0; j < 16; j++) { float dd = z[j] - mu; var += dd * dd; }
        var *= (1.f / 16.f);
        float r = rsqrtf(var + 1e-5f);
        float eo[16];
#pragma unroll
        for (int j = 0; j < 16; j++) {
            float sg_ = sigmoidf_(z[j]);
            den[j] += sg_;
            num[j] += sg_ * mm[j];
            eo[j] = ev[j] + siluf_((z[j] - mu) * r * sL[32 + j] + sL[48 + j]);
        }
        VecIO<TE>::store16(e + (long long)ei * 16, eo);
    }
    // node update: x_new = x + silu(LN(x@W3 + b1 + num/(den+1e-5)))
    float tt[16]; float mu = 0.f;
#pragma unroll
    for (int j = 0; j < 16; j++) {
        float a = sB[16 + j] + num[j] / (den[j] + 1e-5f);
#pragma unroll
        for (int k = 0; k < 16; k++) a += xv[k] * sW[768 + k * 16 + j];
        tt[j] = a; mu += a;
    }
    mu *= (1.f / 16.f);
    float var = 0.f;
#pragma unroll
    for (int j = 0; j < 16; j++) { float dd = tt[j] - mu; var += dd * dd; }
    var *= (1.f / 16.f);
    float r = rsqrtf(var + 1e-5f);
    float ov[16];
#pragma unroll
    for (int j = 0; j < 16; j++)
        ov[j] = xv[j] + siluf_((tt[j] - mu) * r * sL[j] + sL[16 + j]);
    VecIO<TX>::store16(x_new + (long long)d * 16, ov);
}

// ---------- pooling ----------
__global__ void __launch_bounds__(256) k_pool(
    const float* __restrict__ h, const int* __restrict__ batch,
    float* __restrict__ pooled, int n)
{
    int i = blockIdx.x * 256 + threadIdx.x;
    if (i >= n) return;
    int g = batch[i]; g = g < 0 ? 0 : (g > N_GRAPHS - 1 ? N_GRAPHS - 1 : g);
#pragma unroll
    for (int j = 0; j < 16; j++) atomicAdd(&pooled[g * 16 + j], h[(long long)i * 16 + j]);
}

// ---------- head ----------
__global__ void __launch_bounds__(256) k_head(
    const float* __restrict__ pooled, const void* __restrict__ fp,
    const void* l1W, const void* l1b, const void* l2W, const void* l2b,
    const int* __restrict__ flags, void* __restrict__ out)
{
    __shared__ float sW[18 * 16], sb[16], s2W[16];
    int t = threadIdx.x, isbf = flags[0];
    for (int i = t; i < 288; i += 256) sW[i] = loadF(l1W, i, isbf);
    if (t < 16) { sb[t] = loadF(l1b, t, isbf); s2W[t] = loadF(l2W, t, isbf); }
    __syncthreads();
    int g = t;
    if (g >= N_GRAPHS) return;
    float in[18];
#pragma unroll
    for (int j = 0; j < 16; j++) in[j] = pooled[g * 16 + j];
    in[16] = loadF(fp, 2 * g, isbf);
    in[17] = loadF(fp, 2 * g + 1, isbf);
    float acc = loadF(l2b, 0, isbf);
#pragma unroll
    for (int j = 0; j < 16; j++) {
        float h = sb[j];
#pragma unroll
        for (int k = 0; k < 18; k++) h += in[k] * sW[k * 16 + j];
        h = (h > 0.f) ? h : 0.01f * h;
        acc += h * s2W[j];
    }
    if (isbf) ((bf16*)out)[g] = __float2bfloat16(acc);
    else      ((float*)out)[g] = acc;
}

// ---------- pipeline ----------
template <typename TB, typename TA>
static void run_pipeline(void* const* d_in, void* d_out, void* d_ws, hipStream_t stream) {
    const int*  x_atm  = (const int*)d_in[0];
    const void* x_bnd  = d_in[1];
    const void* x_ang  = d_in[2];
    const void* mask   = d_in[3];
    const int*  eiG    = (const int*)d_in[4];
    const int*  eiA    = (const int*)d_in[5];
    const int*  batch  = (const int*)d_in[6];
    const void* fp     = d_in[7];
    const void* eW1    = d_in[8];
    const void* eb1    = d_in[9];
    const void* eW2    = d_in[10];
    const void* eb2    = d_in[11];
    const void* elg    = d_in[12];
    const void* elb    = d_in[13];
    const void* convW  = d_in[14];
    const void* convB  = d_in[15];
    const void* convLN = d_in[16];
    const void* l1W    = d_in[17];
    const void* l1b    = d_in[18];
    const void* l2W    = d_in[19];
    const void* l2b    = d_in[20];

    const size_t NA16 = (size_t)N_ATM * 16;
    const size_t NB16 = (size_t)N_BND * 16;
    const size_t NG16 = (size_t)N_ANG * 16;

    char* p = (char*)d_ws;
    int*   flags  = (int*)p;   p += 64 * 4;
    float* cw     = (float*)p; p += 7680 * 4;
    float* cb     = (float*)p; p += 192 * 4;
    float* cln    = (float*)p; p += 384 * 4;
    float* pooled = (float*)p; p += 4096 * 4;
    int*   bsum   = (int*)p;   p += 4096 * 4;
    int*   cntB   = (int*)p;   p += (size_t)N_BND * 4;   // becomes cursor/end
    int*   ofsB   = (int*)p;   p += (size_t)N_BND * 4;
    int*   eidB   = (int*)p;   p += (size_t)N_ANG * 4;
    int*   cntA   = (int*)p;   p += (size_t)N_ATM * 4;
    int*   ofsA   = (int*)p;   p += (size_t)N_ATM * 4;
    int*   eidA   = (int*)p;   p += (size_t)N_BND * 4;
    float* h_atmA = (float*)p; p += NA16 * 4;
    float* h_atmB = (float*)p; p += NA16 * 4;
    TB*    h_bndA = (TB*)p;    p += NB16 * sizeof(TB);
    TB*    h_bndB = (TB*)p;    p += NB16 * sizeof(TB);
    TA*    h_ang  = (TA*)p;

    // dtype detection (parallel)
    k_zero_int<<<1, 64, 0, stream>>>(flags, 64);
    k_detect<<<512, 256, 0, stream>>>(elg, (const unsigned*)mask, flags);

    // conv params -> f32
    k_cvt_any<<<30, 256, 0, stream>>>(convW, cw, 7680, flags);
    k_cvt_any<<<1, 256, 0, stream>>>(convB, cb, 192, flags);
    k_cvt_any<<<2, 256, 0, stream>>>(convLN, cln, 384, flags);

    // ---- CSR build: bond-node graph (dst of A edges, E=2M, n=1M) ----
    {
        const int* dstA = eiA + N_ANG;
        k_zero_int<<<N_BND / 256, 256, 0, stream>>>(cntB, N_BND);
        k_count<<<N_ANG / 256, 256, 0, stream>>>(dstA, cntB, N_ANG, N_BND);
        int nb = N_BND / 256;  // 4096
        k_scan_local<<<nb, 256, 0, stream>>>(cntB, ofsB, bsum, N_BND);
        k_scan_bsum<<<1, 256, 0, stream>>>(bsum, nb);
        k_scan_add<<<nb, 256, 0, stream>>>(ofsB, bsum, cntB, N_BND);   // cntB := cursor
        k_scatter<<<N_ANG / 256, 256, 0, stream>>>(dstA, cntB, eidB, N_ANG, N_BND);
    }
    // ---- CSR build: atom graph (dst of G edges, E=1M, n=128K) ----
    {
        const int* dstG = eiG + N_BND;
        k_zero_int<<<N_ATM / 256, 256, 0, stream>>>(cntA, N_ATM);
        k_count<<<N_BND / 256, 256, 0, stream>>>(dstG, cntA, N_BND, N_ATM);
        int nb = N_ATM / 256;  // 512
        k_scan_local<<<nb, 256, 0, stream>>>(cntA, ofsA, bsum, N_ATM);
        k_scan_bsum<<<1, 256, 0, stream>>>(bsum, nb);
        k_scan_add<<<nb, 256, 0, stream>>>(ofsA, bsum, cntA, N_ATM);
        k_scatter<<<N_BND / 256, 256, 0, stream>>>(dstG, cntA, eidA, N_BND, N_ATM);
    }

    // ---- encoders ----
    k_enc_atm<<<N_ATM / 256, 256, 0, stream>>>(x_atm, eW1, eb1, eW2, eb2, elg, elb, flags, h_atmA);
    k_enc_bnd<TB><<<N_BND / 256, 256, 0, stream>>>(x_bnd, eW1, eb1, eW2, eb2, elg, elb, flags, h_bndA);
    k_enc_ang<TA><<<N_ANG / 256, 256, 0, stream>>>(x_ang, mask, eW1, eb1, eW2, eb2, elg, elb, flags, h_ang);

    // ---- processor: ping-pong x buffers, e updated in place ----
    float* atmX = h_atmA; float* atmY = h_atmB;
    TB* bndX = h_bndA;    TB* bndY = h_bndB;
    for (int c = 0; c < 3; c++) {
        const float* Wl = cw + (size_t)(c * 2 + 0) * 5 * 256;
        const float* Bl = cb + (size_t)(c * 2 + 0) * 32;
        const float* Ll = cln + (size_t)(c * 2 + 0) * 64;
        // line-graph conv: x = bonds, e = angles
        k_conv<TB, TA><<<N_BND / 256, 256, 0, stream>>>(
            bndX, bndY, h_ang, eiA, eidB, ofsB, cntB, Wl, Bl, Ll, N_BND, N_BND);
        const float* Wa = cw + (size_t)(c * 2 + 1) * 5 * 256;
        const float* Ba = cb + (size_t)(c * 2 + 1) * 32;
        const float* La = cln + (size_t)(c * 2 + 1) * 64;
        // atom-graph conv: x = atoms, e = bonds (the freshly written bndY, in place)
        k_conv<float, TB><<<N_ATM / 256, 256, 0, stream>>>(
            atmX, atmY, bndY, eiG, eidA, ofsA, cntA, Wa, Ba, La, N_ATM, N_ATM);
        { TB* tmp = bndX; bndX = bndY; bndY = tmp; }
        { float* tmp = atmX; atmX = atmY; atmY = tmp; }
    }

    // ---- decoder + head ----
    k_zero<<<4, 256, 0, stream>>>((float4*)pooled, 1024);
    k_pool<<<N_ATM / 256, 256, 0, stream>>>(atmX, batch, pooled, N_ATM);
    k_head<<<1, 256, 0, stream>>>(pooled, fp, l1W, l1b, l2W, l2b, flags, d_out);
}

extern "C" void kernel_launch(void* const* d_in, const int* in_sizes, int n_in,
                              void* d_out, int out_size, void* d_ws, size_t ws_size,
                              hipStream_t stream) {
    const size_t NA16 = (size_t)N_ATM * 16;
    const size_t NB16 = (size_t)N_BND * 16;
    const size_t NG16 = (size_t)N_ANG * 16;
    const size_t smallB = (64 + 7680 + 192 + 384 + 4096 + 4096) * 4;
    const size_t csrB = ((size_t)N_BND * 2 + N_ANG + (size_t)N_ATM * 2 + N_BND) * 4;
    auto need = [&](size_t szB, size_t szA) {
        return smallB + csrB + 2 * NA16 * 4 + 2 * NB16 * szB + NG16 * szA;
    };
    if (ws_size >= need(4, 4))      run_pipeline<float, float>(d_in, d_out, d_ws, stream);
    else if (ws_size >= need(4, 2)) run_pipeline<float, bf16>(d_in, d_out, d_ws, stream);
    else                            run_pipeline<bf16, bf16>(d_in, d_out, d_ws, stream);
}